// Round 1
// baseline (130.049 us; speedup 1.0000x reference)
//
#include <hip/hip_runtime.h>

#define N_X    65536
#define N_IND  1024
#define N_DESC 64
#define NCHUNK 4
#define CHUNK  (N_IND / NCHUNK)   // 256 inducing points per chunk

// ---------------------------------------------------------------------------
// prep: zw[i][k] = z[i][k] * exp(-0.5*ls[k]);  z_sq[i] = sum_k zw^2
// Tiny (1024x64) — one thread per inducing point.
// ---------------------------------------------------------------------------
__global__ void igpr_prep(const float* __restrict__ z,
                          const float* __restrict__ ls,
                          float* __restrict__ zw,
                          float* __restrict__ z_sq) {
    int i = blockIdx.x * blockDim.x + threadIdx.x;
    if (i >= N_IND) return;
    float acc = 0.f;
#pragma unroll
    for (int k = 0; k < N_DESC; ++k) {
        float w = __expf(-0.5f * ls[k]);   // ls[k] uniform -> scalar-cached
        float v = z[i * N_DESC + k] * w;
        zw[i * N_DESC + k] = v;
        acc = fmaf(v, v, acc);
    }
    z_sq[i] = acc;
}

// ---------------------------------------------------------------------------
// main: each thread owns one x point j. xw[64] lives in VGPRs.
// Inner loop over inducing chunk: zw[i][k] is wave-uniform -> s_load into
// SGPRs -> pure v_fma_f32 inner loop (1 SGPR operand each).
// grid = (N_X/256, NCHUNK); partial sums go to ws (deterministic reduce).
// ---------------------------------------------------------------------------
__global__ __launch_bounds__(256) void igpr_main(
        const float* __restrict__ x,
        const float* __restrict__ ls,
        const float* __restrict__ zw,
        const float* __restrict__ z_sq,
        const float* __restrict__ alpha,
        float* __restrict__ part) {
    const int j = blockIdx.x * blockDim.x + threadIdx.x;   // x index
    const int c = blockIdx.y;                              // inducing chunk

    // Load xw into registers; x[j*64 + k] (float4) + uniform ls.
    float xw[N_DESC];
    float xsq = 0.f;
#pragma unroll
    for (int k = 0; k < N_DESC; k += 4) {
        float4 xv = *reinterpret_cast<const float4*>(&x[j * N_DESC + k]);
        float w0 = __expf(-0.5f * ls[k + 0]);
        float w1 = __expf(-0.5f * ls[k + 1]);
        float w2 = __expf(-0.5f * ls[k + 2]);
        float w3 = __expf(-0.5f * ls[k + 3]);
        xw[k + 0] = xv.x * w0;
        xw[k + 1] = xv.y * w1;
        xw[k + 2] = xv.z * w2;
        xw[k + 3] = xv.w * w3;
        xsq = fmaf(xw[k + 0], xw[k + 0], xsq);
        xsq = fmaf(xw[k + 1], xw[k + 1], xsq);
        xsq = fmaf(xw[k + 2], xw[k + 2], xsq);
        xsq = fmaf(xw[k + 3], xw[k + 3], xsq);
    }

    float acc = 0.f;
    const int i0 = c * CHUNK;
    for (int i = i0; i < i0 + CHUNK; ++i) {
        const float* zr = &zw[i * N_DESC];   // uniform address across wave
        float d0 = 0.f, d1 = 0.f, d2 = 0.f, d3 = 0.f;
#pragma unroll
        for (int k = 0; k < N_DESC; k += 4) {
            d0 = fmaf(xw[k + 0], zr[k + 0], d0);
            d1 = fmaf(xw[k + 1], zr[k + 1], d1);
            d2 = fmaf(xw[k + 2], zr[k + 2], d2);
            d3 = fmaf(xw[k + 3], zr[k + 3], d3);
        }
        float dot = (d0 + d1) + (d2 + d3);
        float d   = z_sq[i] + xsq - 2.f * dot;
        acc = fmaf(alpha[i], __expf(-d), acc);
    }
    part[(size_t)c * N_X + j] = acc;
}

// ---------------------------------------------------------------------------
// reduce: out[j] = sum_c part[c][j]
// ---------------------------------------------------------------------------
__global__ void igpr_reduce(const float* __restrict__ part,
                            float* __restrict__ out) {
    int j = blockIdx.x * blockDim.x + threadIdx.x;
    float s = 0.f;
#pragma unroll
    for (int c = 0; c < NCHUNK; ++c) s += part[(size_t)c * N_X + j];
    out[j] = s;
}

extern "C" void kernel_launch(void* const* d_in, const int* in_sizes, int n_in,
                              void* d_out, int out_size, void* d_ws, size_t ws_size,
                              hipStream_t stream) {
    const float* x     = (const float*)d_in[0];   // (65536, 64)
    const float* z     = (const float*)d_in[1];   // (1024, 64)
    const float* alpha = (const float*)d_in[2];   // (1024,)
    const float* ls    = (const float*)d_in[3];   // (64,)
    float* out = (float*)d_out;                   // (65536,)

    // ws layout (floats): zw[65536] | z_sq[1024] | part[NCHUNK*65536]
    float* zw   = (float*)d_ws;
    float* z_sq = zw + (size_t)N_IND * N_DESC;
    float* part = z_sq + N_IND;

    igpr_prep<<<dim3((N_IND + 255) / 256), dim3(256), 0, stream>>>(z, ls, zw, z_sq);

    dim3 grid(N_X / 256, NCHUNK);
    igpr_main<<<grid, dim3(256), 0, stream>>>(x, ls, zw, z_sq, alpha, part);

    igpr_reduce<<<dim3(N_X / 256), dim3(256), 0, stream>>>(part, out);
}

// Round 2
// 68.194 us; speedup vs baseline: 1.9070x; 1.9070x over previous
//
#include <hip/hip_runtime.h>
#include <hip/hip_bf16.h>

#define N_X    65536
#define N_IND  1024
#define N_DESC 64
#define NCHUNK 4
#define CHUNK  (N_IND / NCHUNK)   // 256 inducing points per i-chunk
#define TILES  (CHUNK / 16)       // 16 MFMA row-tiles per chunk
#define L2E    1.4426950408889634f
#define L2E2   2.8853900817779268f

typedef __attribute__((ext_vector_type(8))) short  short8;
typedef __attribute__((ext_vector_type(4))) float  f32x4;

static __device__ __forceinline__ ushort f2bf(float f) {
    union { float f; unsigned u; } a; a.f = f;
    unsigned r = a.u + 0x7FFF + ((a.u >> 16) & 1);   // RNE to bf16
    return (ushort)(r >> 16);
}
static __device__ __forceinline__ float bf2f(ushort h) {
    union { unsigned u; float f; } a; a.u = (unsigned)h << 16;
    return a.f;
}

// ---------------------------------------------------------------------------
// prep_z: zwb[i][k] = bf16(z[i][k]*exp(-ls[k]/2));  zs2[i] = log2e*sum(zw_r^2)
// 4 lanes per row (16 k each), shfl-reduce the square sum.
// ---------------------------------------------------------------------------
__global__ __launch_bounds__(256) void igpr_prep_z(
        const float* __restrict__ z, const float* __restrict__ ls,
        ushort* __restrict__ zwb, float* __restrict__ zs2) {
    int tid = blockIdx.x * 256 + threadIdx.x;
    int r = tid >> 2, q = tid & 3;          // r < 1024, q = k-quarter
    float sq = 0.f;
    ushort hb[16];
#pragma unroll
    for (int m = 0; m < 4; ++m) {
        float4 zv = *reinterpret_cast<const float4*>(&z[r * N_DESC + q * 16 + m * 4]);
        float vv[4] = {zv.x, zv.y, zv.z, zv.w};
#pragma unroll
        for (int e = 0; e < 4; ++e) {
            float w = __expf(-0.5f * ls[q * 16 + m * 4 + e]);
            ushort h = f2bf(vv[e] * w);
            hb[m * 4 + e] = h;
            float vr = bf2f(h);
            sq = fmaf(vr, vr, sq);
        }
    }
    unsigned u[8];
#pragma unroll
    for (int t = 0; t < 8; ++t)
        u[t] = (unsigned)hb[2 * t] | ((unsigned)hb[2 * t + 1] << 16);
    uint4* dst = reinterpret_cast<uint4*>(&zwb[r * N_DESC + q * 16]);
    dst[0] = make_uint4(u[0], u[1], u[2], u[3]);
    dst[1] = make_uint4(u[4], u[5], u[6], u[7]);
    sq += __shfl_xor(sq, 1);
    sq += __shfl_xor(sq, 2);
    if (q == 0) zs2[r] = sq * L2E;
}

// ---------------------------------------------------------------------------
// main: wave owns 64 x-columns (4 strips of 16); B-frags live in VGPRs for
// the whole kernel. Loop over 16 row-tiles of this block's i-chunk:
//   acc = mfma(zwA, xwB) ; arg = 2*log2e*acc - (zs2[i] + xs2[j]) ;
//   accJ += alpha[i] * exp2(arg)
// C/D layout (verified): col = lane&15, row = 4*(lane>>4) + reg.
// ---------------------------------------------------------------------------
__global__ __launch_bounds__(256) void igpr_main(
        const float* __restrict__ x, const float* __restrict__ ls,
        const ushort* __restrict__ zwb, const float* __restrict__ zs2,
        const float* __restrict__ alpha, float* __restrict__ part) {
    const int lane = threadIdx.x & 63;
    const int wave = threadIdx.x >> 6;
    const int p = lane & 15;          // point index within strip
    const int g = lane >> 4;          // k-group
    const int j0 = blockIdx.x * 256 + wave * 64;
    const int c  = blockIdx.y;        // i-chunk

    // per-lane lengthscale weights for its 16 k's
    float wk[16];
#pragma unroll
    for (int h = 0; h < 2; ++h)
#pragma unroll
        for (int e = 0; e < 8; ++e)
            wk[h * 8 + e] = __expf(-0.5f * ls[h * 32 + g * 8 + e]);

    // B fragments (xw in bf16) + per-column x_sq * log2e
    short8 b[4][2];
    float xs2[4];
#pragma unroll
    for (int s = 0; s < 4; ++s) {
        int j = j0 + s * 16 + p;
        float sq = 0.f;
#pragma unroll
        for (int h = 0; h < 2; ++h) {
            float4 v0 = *reinterpret_cast<const float4*>(&x[j * N_DESC + h * 32 + g * 8]);
            float4 v1 = *reinterpret_cast<const float4*>(&x[j * N_DESC + h * 32 + g * 8 + 4]);
            float vv[8] = {v0.x, v0.y, v0.z, v0.w, v1.x, v1.y, v1.z, v1.w};
            short8 bb;
#pragma unroll
            for (int e = 0; e < 8; ++e) {
                ushort hh = f2bf(vv[e] * wk[h * 8 + e]);
                bb[e] = (short)hh;
                float xr = bf2f(hh);
                sq = fmaf(xr, xr, sq);
            }
            b[s][h] = bb;
        }
        sq += __shfl_xor(sq, 16);   // sum over the 4 k-groups
        sq += __shfl_xor(sq, 32);
        xs2[s] = sq * L2E;
    }

    float accJ[4] = {0.f, 0.f, 0.f, 0.f};
    for (int it = 0; it < TILES; ++it) {
        const int i0 = c * CHUNK + it * 16;
        const ushort* zr = zwb + (size_t)(i0 + p) * N_DESC;
        short8 a0 = *reinterpret_cast<const short8*>(zr + g * 8);
        short8 a1 = *reinterpret_cast<const short8*>(zr + 32 + g * 8);
        f32x4 acc[4];
#pragma unroll
        for (int s = 0; s < 4; ++s) {
            f32x4 t = {0.f, 0.f, 0.f, 0.f};
            t = __builtin_amdgcn_mfma_f32_16x16x32_bf16(a0, b[s][0], t, 0, 0, 0);
            t = __builtin_amdgcn_mfma_f32_16x16x32_bf16(a1, b[s][1], t, 0, 0, 0);
            acc[s] = t;
        }
        float4 z2 = *reinterpret_cast<const float4*>(&zs2[i0 + g * 4]);
        float4 a4 = *reinterpret_cast<const float4*>(&alpha[i0 + g * 4]);
        float z2v[4] = {z2.x, z2.y, z2.z, z2.w};
        float a4v[4] = {a4.x, a4.y, a4.z, a4.w};
#pragma unroll
        for (int s = 0; s < 4; ++s) {
#pragma unroll
            for (int e = 0; e < 4; ++e) {
                float arg = fmaf(acc[s][e], L2E2, -(z2v[e] + xs2[s]));
                float pv  = __builtin_amdgcn_exp2f(arg);
                accJ[s]   = fmaf(a4v[e], pv, accJ[s]);
            }
        }
    }

#pragma unroll
    for (int s = 0; s < 4; ++s) {
        float r = accJ[s];
        r += __shfl_xor(r, 16);
        r += __shfl_xor(r, 32);
        if (g == 0) part[(size_t)c * N_X + j0 + s * 16 + p] = r;
    }
}

// ---------------------------------------------------------------------------
// reduce: out[j] = sum_c part[c][j]
// ---------------------------------------------------------------------------
__global__ void igpr_reduce(const float* __restrict__ part,
                            float* __restrict__ out) {
    int j = blockIdx.x * 256 + threadIdx.x;
    float s = 0.f;
#pragma unroll
    for (int c = 0; c < NCHUNK; ++c) s += part[(size_t)c * N_X + j];
    out[j] = s;
}

extern "C" void kernel_launch(void* const* d_in, const int* in_sizes, int n_in,
                              void* d_out, int out_size, void* d_ws, size_t ws_size,
                              hipStream_t stream) {
    const float* x     = (const float*)d_in[0];   // (65536, 64)
    const float* z     = (const float*)d_in[1];   // (1024, 64)
    const float* alpha = (const float*)d_in[2];   // (1024,)
    const float* ls    = (const float*)d_in[3];   // (64,)
    float* out = (float*)d_out;                   // (65536, 1)

    // ws layout: zwb (ushort, 1024*64 = 128KB) | zs2 (1024 f32) | part (4*65536 f32)
    ushort* zwb  = (ushort*)d_ws;
    float*  zs2  = (float*)(zwb + (size_t)N_IND * N_DESC);
    float*  part = zs2 + N_IND;

    igpr_prep_z<<<dim3(16), dim3(256), 0, stream>>>(z, ls, zwb, zs2);
    igpr_main<<<dim3(N_X / 256, NCHUNK), dim3(256), 0, stream>>>(x, ls, zwb, zs2, alpha, part);
    igpr_reduce<<<dim3(N_X / 256), dim3(256), 0, stream>>>(part, out);
}